// Round 1
// baseline (66.458 us; speedup 1.0000x reference)
//
#include <hip/hip_runtime.h>
#include <hip/hip_bf16.h>

// CosSim2D: inputs (32,64,64,64) f32, w (1,576,128) f32, p (128), q (1)
// out (32,64,64,128) f32.
// Strategy: bf16 MFMA GEMM with implicit im2col from an LDS-staged 3-row tile.

typedef short bf16x8 __attribute__((ext_vector_type(8)));
typedef float f32x4 __attribute__((ext_vector_type(4)));

__device__ __forceinline__ unsigned short f2bf(float f) {
    union { float f; unsigned int u; } v; v.f = f;
    unsigned int u = v.u;
    unsigned int r = (u + 0x7fffu + ((u >> 16) & 1u)) >> 16;  // RNE
    return (unsigned short)r;
}

__device__ __forceinline__ float bf2f(unsigned short h) {
    union { unsigned int u; float f; } v; v.u = ((unsigned int)h) << 16;
    return v.f;
}

// ---- pre-kernel: normalize w columns (fp32), store as bf16 wn[n][k], k contiguous
__global__ void prep_w_kernel(const float* __restrict__ w,
                              unsigned short* __restrict__ wn) {
    const int n = blockIdx.x;       // 0..127
    const int lane = threadIdx.x;   // 0..63 (one wave)
    float vals[9];
    float s = 0.f;
#pragma unroll
    for (int i = 0; i < 9; ++i) {
        float v = w[(i * 64 + lane) * 128 + n];   // w[k][n], k = i*64+lane
        vals[i] = v;
        s += v * v;
    }
#pragma unroll
    for (int off = 1; off < 64; off <<= 1) s += __shfl_xor(s, off);
    const float inv = 1.0f / sqrtf(fmaxf(s, 1e-12f));
#pragma unroll
    for (int i = 0; i < 9; ++i)
        wn[n * 576 + i * 64 + lane] = f2bf(vals[i] * inv);
}

// ---- main kernel: one block per (b, y) image row; 64 pixels x 128 kernels
__global__ __launch_bounds__(256) void cossim_main(
    const float* __restrict__ in, const unsigned short* __restrict__ wn,
    const float* __restrict__ p, const float* __restrict__ q,
    float* __restrict__ out) {
    // LDS A: [3 rows][66 cols (zero-pad col 0 & 65)][72 ch (64 + 16B pad)]
    __shared__ unsigned short A[3 * 66 * 72];   // 28512 B
    __shared__ float part[256];
    __shared__ float xni[64];
    __shared__ float pfs[128];

    const int tid = (int)threadIdx.x;
    // T1 bijective XCD swizzle: 2048 blocks, 8 XCDs -> 256 consecutive logical
    // rows per XCD (y-adjacent blocks share 2 of 3 input rows -> L2 hits).
    const int l = ((int)blockIdx.x & 7) * 256 + ((int)blockIdx.x >> 3);
    const int b = l >> 6, y = l & 63;

    const float qe = expf(q[0] * (-1.0f / 0.3f));   // exp(-q/Q_SCALE)
    if (tid < 128) pfs[tid] = expf(p[tid] * 0.2f);  // exp(p/P_SCALE)

    // ---- stage 3 input rows (y-1,y,y+1) into LDS as bf16
#pragma unroll
    for (int it = 0; it < 12; ++it) {
        int s = tid + it * 256;          // 0..3071 float4 slots
        int r = s >> 10;                 // which of 3 rows
        int rem = s & 1023;
        int col = rem >> 4;              // 0..63
        int c4 = (rem & 15) << 2;        // channel base 0..60
        int row = y + r - 1;
        float4 v = make_float4(0.f, 0.f, 0.f, 0.f);
        if ((unsigned)row < 64u)
            v = *reinterpret_cast<const float4*>(
                in + (size_t)b * 262144 + row * 4096 + col * 64 + c4);
        unsigned int lo = (unsigned int)f2bf(v.x) | ((unsigned int)f2bf(v.y) << 16);
        unsigned int hi = (unsigned int)f2bf(v.z) | ((unsigned int)f2bf(v.w) << 16);
        uint2 pk; pk.x = lo; pk.y = hi;
        *reinterpret_cast<uint2*>(&A[r * 4752 + (col + 1) * 72 + c4]) = pk;
    }
    if (tid < 96) {  // zero border cols 0 and 65 (channels 0..63)
        int r = tid >> 5;
        int side = (tid >> 4) & 1;
        int c4 = (tid & 15) << 2;
        uint2 z; z.x = 0u; z.y = 0u;
        *reinterpret_cast<uint2*>(&A[r * 4752 + side * (65 * 72) + c4]) = z;
    }
    __syncthreads();

    // ---- per-pixel 1/(||x||+q_eff); 4 threads per pixel, 16 channels each
    {
        const int x = tid & 63, qt = tid >> 6;
        float s = 0.f;
#pragma unroll
        for (int rr = 0; rr < 3; ++rr) {
#pragma unroll
            for (int dc = 0; dc < 3; ++dc) {
                const unsigned short* pa = &A[rr * 4752 + (x + dc) * 72 + qt * 16];
                bf16x8 v0 = *reinterpret_cast<const bf16x8*>(pa);
                bf16x8 v1 = *reinterpret_cast<const bf16x8*>(pa + 8);
#pragma unroll
                for (int j = 0; j < 8; ++j) {
                    float f0 = bf2f((unsigned short)v0[j]);
                    float f1 = bf2f((unsigned short)v1[j]);
                    s += f0 * f0 + f1 * f1;
                }
            }
        }
        part[tid] = s;
    }
    __syncthreads();
    if (tid < 64) {
        float s = part[tid] + part[tid + 64] + part[tid + 128] + part[tid + 192];
        xni[tid] = 1.0f / (sqrtf(fmaxf(s, 1e-12f)) + qe);
    }
    __syncthreads();

    // ---- MFMA main loop: wave wv owns N columns [wv*32, wv*32+32)
    const int wv = tid >> 6, lane = tid & 63;
    const int lr = lane & 15, lg = lane >> 4;
    f32x4 acc[4][2] = {};
    const unsigned short* w0 = wn + (wv * 32 + lr) * 576;
    const unsigned short* w1 = w0 + 16 * 576;

#pragma unroll
    for (int dy = 0; dy < 3; ++dy) {
#pragma unroll
        for (int dx = 0; dx < 3; ++dx) {
            const int tap = dy * 3 + dx;
#pragma unroll
            for (int kc = 0; kc < 2; ++kc) {
                const int kb = tap * 64 + kc * 32 + lg * 8;
                bf16x8 bf0 = *reinterpret_cast<const bf16x8*>(w0 + kb);
                bf16x8 bf1 = *reinterpret_cast<const bf16x8*>(w1 + kb);
                const int cb = kc * 32 + lg * 8;
#pragma unroll
                for (int mf = 0; mf < 4; ++mf) {
                    const int col = lr + 16 * mf + dx;  // +dx == im2col shift (pad +1)
                    bf16x8 av = *reinterpret_cast<const bf16x8*>(
                        &A[dy * 4752 + col * 72 + cb]);
                    acc[mf][0] = __builtin_amdgcn_mfma_f32_16x16x32_bf16(
                        av, bf0, acc[mf][0], 0, 0, 0);
                    acc[mf][1] = __builtin_amdgcn_mfma_f32_16x16x32_bf16(
                        av, bf1, acc[mf][1], 0, 0, 0);
                }
            }
        }
    }

    // ---- epilogue: sim = acc/||x||; out = sign(sim)*(|sim|+eps)^p_eff
    const size_t outbase = (size_t)l * 8192;
#pragma unroll
    for (int mf = 0; mf < 4; ++mf) {
#pragma unroll
        for (int nf = 0; nf < 2; ++nf) {
            const int n = wv * 32 + nf * 16 + lr;
            const float pn = pfs[n];
#pragma unroll
            for (int i = 0; i < 4; ++i) {
                const int x = mf * 16 + lg * 4 + i;  // C/D: row=(lane>>4)*4+reg
                float sim = acc[mf][nf][i] * xni[x];
                float aa = fabsf(sim) + 1e-6f;
                float r = exp2f(pn * log2f(aa));
                out[outbase + (size_t)x * 128 + n] = copysignf(r, sim);
            }
        }
    }
}

extern "C" void kernel_launch(void* const* d_in, const int* in_sizes, int n_in,
                              void* d_out, int out_size, void* d_ws, size_t ws_size,
                              hipStream_t stream) {
    (void)in_sizes; (void)n_in; (void)out_size; (void)ws_size;
    const float* in = (const float*)d_in[0];
    const float* w  = (const float*)d_in[1];
    const float* p  = (const float*)d_in[2];
    const float* q  = (const float*)d_in[3];
    float* out = (float*)d_out;
    unsigned short* wn = (unsigned short*)d_ws;  // 128*576 bf16 = 147456 B

    prep_w_kernel<<<128, 64, 0, stream>>>(w, wn);
    cossim_main<<<2048, 256, 0, stream>>>(in, wn, p, q, out);
}

// Round 2
// 58.820 us; speedup vs baseline: 1.1299x; 1.1299x over previous
//
#include <hip/hip_runtime.h>
#include <hip/hip_bf16.h>

// CosSim2D: inputs (32,64,64,64) f32, w (1,576,128) f32, p (128), q (1)
// out (32,64,64,128) f32.
// bf16 MFMA GEMM, implicit im2col from LDS-staged 4-row tile, 2 output rows
// per block, norm fused into staging.

typedef short bf16x8 __attribute__((ext_vector_type(8)));
typedef float f32x4 __attribute__((ext_vector_type(4)));

__device__ __forceinline__ unsigned short f2bf(float f) {
    union { float f; unsigned int u; } v; v.f = f;
    unsigned int u = v.u;
    unsigned int r = (u + 0x7fffu + ((u >> 16) & 1u)) >> 16;  // RNE
    return (unsigned short)r;
}

// ---- pre-kernel: normalize w columns (fp32), store bf16 wn[n][k], k contiguous
__global__ void prep_w_kernel(const float* __restrict__ w,
                              unsigned short* __restrict__ wn) {
    const int n = blockIdx.x;       // 0..127
    const int lane = threadIdx.x;   // 0..63
    float vals[9];
    float s = 0.f;
#pragma unroll
    for (int i = 0; i < 9; ++i) {
        float v = w[(i * 64 + lane) * 128 + n];
        vals[i] = v;
        s += v * v;
    }
#pragma unroll
    for (int off = 1; off < 64; off <<= 1) s += __shfl_xor(s, off);
    const float inv = 1.0f / sqrtf(fmaxf(s, 1e-12f));
#pragma unroll
    for (int i = 0; i < 9; ++i)
        wn[n * 576 + i * 64 + lane] = f2bf(vals[i] * inv);
}

// ---- main: one block = (image b, output rows y0,y0+1); 128 pixels x 128 n
__global__ __launch_bounds__(256, 4) void cossim_main(
    const float* __restrict__ in, const unsigned short* __restrict__ wn,
    const float* __restrict__ p, const float* __restrict__ q,
    float* __restrict__ out) {
    // A: [4 rows][66 cols (zero-pad 0,65)][72 ch (64 + 16B pad)] bf16 = 38016 B
    __shared__ unsigned short A[4 * 66 * 72];
    __shared__ float rcsum[256];   // per-(row,col) fp32 square-sums
    __shared__ float xni[128];     // per-pixel 1/(||x||+q_eff)
    __shared__ float pfs[128];     // exp(p/P_SCALE)

    const int tid = (int)threadIdx.x;
    // bijective XCD swizzle: 1024 blocks, 8 XCDs, 128 consecutive l per XCD
    const int l = ((int)blockIdx.x & 7) * 128 + ((int)blockIdx.x >> 3);
    const int b = l >> 5, y0 = (l & 31) * 2;

    if (tid < 128) pfs[tid] = expf(p[tid] * 0.2f);

    // ---- stage 4 input rows (y0-1 .. y0+2) + fused fp32 norm partials
    {
        const int r = tid >> 6;        // staged row 0..3
        const int col = tid & 63;
        const int row = y0 + r - 1;
        unsigned short* dst = &A[(r * 66 + col + 1) * 72];
        float s = 0.f;
        if ((unsigned)row < 64u) {
            const float4* src = reinterpret_cast<const float4*>(
                in + (size_t)b * 262144 + row * 4096 + col * 64);
#pragma unroll
            for (int it = 0; it < 8; ++it) {
                float4 v0 = src[2 * it];
                float4 v1 = src[2 * it + 1];
                s += v0.x * v0.x + v0.y * v0.y + v0.z * v0.z + v0.w * v0.w;
                s += v1.x * v1.x + v1.y * v1.y + v1.z * v1.z + v1.w * v1.w;
                union { float f; unsigned u; } ux, uy, uz, uw;
                uint4 pk;
                ux.f = v0.x; uy.f = v0.y; uz.f = v0.z; uw.f = v0.w;
                pk.x = __builtin_amdgcn_perm(uy.u + 0x8000u, ux.u + 0x8000u, 0x07060302u);
                pk.y = __builtin_amdgcn_perm(uw.u + 0x8000u, uz.u + 0x8000u, 0x07060302u);
                ux.f = v1.x; uy.f = v1.y; uz.f = v1.z; uw.f = v1.w;
                pk.z = __builtin_amdgcn_perm(uy.u + 0x8000u, ux.u + 0x8000u, 0x07060302u);
                pk.w = __builtin_amdgcn_perm(uw.u + 0x8000u, uz.u + 0x8000u, 0x07060302u);
                *reinterpret_cast<uint4*>(dst + it * 8) = pk;
            }
        } else {
            uint4 z; z.x = z.y = z.z = z.w = 0u;
#pragma unroll
            for (int it = 0; it < 8; ++it)
                *reinterpret_cast<uint4*>(dst + it * 8) = z;
        }
        rcsum[tid] = s;
    }
    if (tid < 64) {  // zero border cols 0 and 65, all 4 rows
        const int r = tid >> 4, side = (tid >> 3) & 1, ch = (tid & 7) * 8;
        uint4 z; z.x = z.y = z.z = z.w = 0u;
        *reinterpret_cast<uint4*>(&A[(r * 66 + side * 65) * 72 + ch]) = z;
    }
    __syncthreads();

    // ---- per-pixel 1/(||x||+q_eff) from fp32 partials (overlaps MFMA issue)
    if (tid < 128) {
        const int ry = tid >> 6, x = tid & 63;
        const float qe = expf(q[0] * (-1.0f / 0.3f));
        float s = 0.f;
#pragma unroll
        for (int dy = 0; dy < 3; ++dy) {
            const float* rs = &rcsum[(ry + dy) * 64];
            if (x > 0) s += rs[x - 1];
            s += rs[x];
            if (x < 63) s += rs[x + 1];
        }
        xni[tid] = 1.0f / (sqrtf(fmaxf(s, 1e-12f)) + qe);
    }

    // ---- MFMA loop: wave grid 2M x 2N; wave owns 64 pixels x 64 n
    const int wv = tid >> 6, lane = tid & 63;
    const int lr = lane & 15, lg = lane >> 4;
    const int wm = wv >> 1, wnh = wv & 1;
    f32x4 acc[4][4] = {};
    const unsigned short* wb = wn + (wnh * 64 + lr) * 576;

#pragma unroll
    for (int dy = 0; dy < 3; ++dy) {
#pragma unroll
        for (int dx = 0; dx < 3; ++dx) {
            const int tap = dy * 3 + dx;
#pragma unroll
            for (int kc = 0; kc < 2; ++kc) {
                const int kb = tap * 64 + kc * 32 + lg * 8;
                bf16x8 b0 = *reinterpret_cast<const bf16x8*>(wb + kb);
                bf16x8 b1 = *reinterpret_cast<const bf16x8*>(wb + 16 * 576 + kb);
                bf16x8 b2 = *reinterpret_cast<const bf16x8*>(wb + 32 * 576 + kb);
                bf16x8 b3 = *reinterpret_cast<const bf16x8*>(wb + 48 * 576 + kb);
                const unsigned short* abase =
                    &A[((wm + dy) * 66 + lr + dx) * 72 + kc * 32 + lg * 8];
#pragma unroll
                for (int mf = 0; mf < 4; ++mf) {
                    bf16x8 av = *reinterpret_cast<const bf16x8*>(abase + mf * 16 * 72);
                    acc[mf][0] = __builtin_amdgcn_mfma_f32_16x16x32_bf16(av, b0, acc[mf][0], 0, 0, 0);
                    acc[mf][1] = __builtin_amdgcn_mfma_f32_16x16x32_bf16(av, b1, acc[mf][1], 0, 0, 0);
                    acc[mf][2] = __builtin_amdgcn_mfma_f32_16x16x32_bf16(av, b2, acc[mf][2], 0, 0, 0);
                    acc[mf][3] = __builtin_amdgcn_mfma_f32_16x16x32_bf16(av, b3, acc[mf][3], 0, 0, 0);
                }
            }
        }
    }
    __syncthreads();   // xni/pfs visibility before epilogue

    // ---- epilogue: sim = acc * xni; out = sign * (|sim|+eps)^p_eff
    float* orow = out + ((size_t)(b * 64 + y0 + wm) * 64) * 128;
#pragma unroll
    for (int mf = 0; mf < 4; ++mf) {
#pragma unroll
        for (int i = 0; i < 4; ++i) {
            const int pix = mf * 16 + lg * 4 + i;   // C/D: row=(lane>>4)*4+reg
            const float xn = xni[wm * 64 + pix];
#pragma unroll
            for (int nf = 0; nf < 4; ++nf) {
                const int n = wnh * 64 + nf * 16 + lr;
                float sim = acc[mf][nf][i] * xn;
                float aa = fabsf(sim) + 1e-6f;
                float r = exp2f(pfs[n] * log2f(aa));
                orow[(size_t)pix * 128 + n] = copysignf(r, sim);
            }
        }
    }
}

extern "C" void kernel_launch(void* const* d_in, const int* in_sizes, int n_in,
                              void* d_out, int out_size, void* d_ws, size_t ws_size,
                              hipStream_t stream) {
    (void)in_sizes; (void)n_in; (void)out_size; (void)ws_size;
    const float* in = (const float*)d_in[0];
    const float* w  = (const float*)d_in[1];
    const float* p  = (const float*)d_in[2];
    const float* q  = (const float*)d_in[3];
    float* out = (float*)d_out;
    unsigned short* wn = (unsigned short*)d_ws;  // 128*576 bf16 = 147456 B

    prep_w_kernel<<<128, 64, 0, stream>>>(w, wn);
    cossim_main<<<1024, 256, 0, stream>>>(in, wn, p, q, out);
}